// Round 6
// baseline (235.059 us; speedup 1.0000x reference)
//
#include <hip/hip_runtime.h>
#include <math.h>

#define BN_EPS 1e-5f
#define NEG_SLOPE 0.2f

__device__ __forceinline__ float relu_f(float x) { return x > 0.f ? x : 0.f; }
__device__ __forceinline__ float leaky_f(float z) { return z > 0.f ? z : NEG_SLOPE * z; }

// ---------------- conv1 (3->64, 3x3 SAME) fused bias+BN+ReLU+2x2maxpool ----------------
// grid 512 = b(8) x cog(16) x q(4); 256 threads = one pooled position, 4 co
__global__ void conv1_pool(const float* __restrict__ img, const float* __restrict__ w,
                           const float* __restrict__ cb, const float* __restrict__ g,
                           const float* __restrict__ bb, const float* __restrict__ m,
                           const float* __restrict__ vv, float* __restrict__ out)
{
    int blk = blockIdx.x;
    int q = blk & 3, cog = (blk >> 2) & 15, b = blk >> 6;
    int t = threadIdx.x;
    int x = t & 31, y = (q << 3) + (t >> 5);

    float acc[4][4] = {};
#pragma unroll
    for (int ci = 0; ci < 3; ++ci) {
        const float* ib = img + (b * 3 + ci) * 4096;
        float rv[4][4];
#pragma unroll
        for (int r = 0; r < 4; ++r) {
            int yy = 2 * y - 1 + r;
            bool yok = (unsigned)yy < 64u;
            const float* p = ib + yy * 64 + 2 * x;
            float2 c01 = yok ? *(const float2*)p : make_float2(0.f, 0.f);
            rv[r][1] = c01.x;
            rv[r][2] = c01.y;
            rv[r][0] = (yok && x > 0) ? p[-1] : 0.f;
            rv[r][3] = (yok && x < 31) ? p[2] : 0.f;
        }
#pragma unroll
        for (int j = 0; j < 4; ++j) {
            const float* wj = w + ((cog * 4 + j) * 3 + ci) * 9;
#pragma unroll
            for (int ky = 0; ky < 3; ++ky)
#pragma unroll
                for (int kx = 0; kx < 3; ++kx) {
                    float wvv = wj[ky * 3 + kx];
#pragma unroll
                    for (int py = 0; py < 2; ++py)
#pragma unroll
                        for (int px = 0; px < 2; ++px)
                            acc[j][py * 2 + px] += rv[py + ky][px + kx] * wvv;
                }
        }
    }
#pragma unroll
    for (int j = 0; j < 4; ++j) {
        int co = cog * 4 + j;
        float inv = g[co] / sqrtf(vv[co] + BN_EPS);
        float sh = cb[co] * inv + (bb[co] - m[co] * inv);
        float v0 = relu_f(acc[j][0] * inv + sh);
        float v1 = relu_f(acc[j][1] * inv + sh);
        float v2 = relu_f(acc[j][2] * inv + sh);
        float v3 = relu_f(acc[j][3] * inv + sh);
        out[((b * 64 + co) * 32 + y) * 32 + x] = fmaxf(fmaxf(v0, v1), fmaxf(v2, v3));
    }
}

// ---------------- conv2: 64->128, 3x3 SAME, SPLIT-K over ci (2 ways) ----------------
// grid 1024 = b(8) x cog(32) x half(2) x kz(2); 256 threads; each block reduces 32 ci.
// Partials BLOCK-LINEAR (fully coalesced): plane[kz] at ((bid*256+t)*8), bid=b*64+cog*2+half
__global__ void conv2_split(const float* __restrict__ in, const float* __restrict__ w,
                            float* __restrict__ c2p)
{
    int blk = blockIdx.x;
    int kz = blk & 1, half = (blk >> 1) & 1, cog = (blk >> 2) & 31, b = blk >> 7;
    int t = threadIdx.x;
    int x2p = (t & 15) * 2;
    int y = half * 16 + (t >> 4);
    bool xnz = x2p != 0;
    bool xhi = x2p == 30;
    const float* ibase = in + b * 65536 + kz * 32768;
    int xb = xnz ? x2p - 1 : 0;

    float acc[4][2] = {};

#pragma unroll 2
    for (int ci = 0; ci < 32; ++ci) {
        const float* cb2 = ibase + ci * 1024;
        float rc[3][4];
#pragma unroll
        for (int r = 0; r < 3; ++r) {
            int yy = y - 1 + r;
            bool yok = (unsigned)yy < 32u;
            const float* p = cb2 + yy * 32 + xb;
            float4 f = yok ? *(const float4*)p : make_float4(0.f, 0.f, 0.f, 0.f);
            rc[r][0] = xnz ? f.x : 0.f;
            rc[r][1] = xnz ? f.y : f.x;
            rc[r][2] = xnz ? f.z : f.y;
            float r3 = xnz ? f.w : f.z;
            rc[r][3] = xhi ? 0.f : r3;
        }
#pragma unroll
        for (int j = 0; j < 4; ++j) {
            const float* wj = w + ((cog * 4 + j) * 64 + kz * 32 + ci) * 9;
#pragma unroll
            for (int ky = 0; ky < 3; ++ky)
#pragma unroll
                for (int kx = 0; kx < 3; ++kx) {
                    float wvv = wj[ky * 3 + kx];
                    acc[j][0] += rc[ky][kx] * wvv;
                    acc[j][1] += rc[ky][kx + 1] * wvv;
                }
        }
    }

    float* pp = c2p + (size_t)kz * 1048576;
    int bid = b * 64 + cog * 2 + half;
    size_t base = ((size_t)bid * 256 + t) * 8;
    float4 s0 = {acc[0][0], acc[1][0], acc[2][0], acc[3][0]};
    float4 s1 = {acc[0][1], acc[1][1], acc[2][1], acc[3][1]};
    *(float4*)&pp[base] = s0;
    *(float4*)&pp[base + 4] = s1;
}

// ---------------- gemm1: h1 = relu(BN(conv2partials)) @ g1w, fused combine + scores -------
// A[m][k] built on load from the 2 conv2 planes: relu((p0+p1)*inv[k] + sh[k]).
// Plane address per thread collapses to const + k0*1024.
// grid (256, 4), 256 threads (4 waves); 32x64 tile, 2x4 micro.
// Score epilogue (m0<1024): sp[by*1024+row] = sum_cols C*asrc (dp likewise).
__global__ void gemm1_conv(const float* __restrict__ c2p,
                           const float* __restrict__ cb, const float* __restrict__ g,
                           const float* __restrict__ bb, const float* __restrict__ mbn,
                           const float* __restrict__ vv,
                           const float* __restrict__ B, float* __restrict__ C,
                           const float* __restrict__ asrc, const float* __restrict__ adst,
                           float* __restrict__ sp, float* __restrict__ dp)
{
    __shared__ float As[16][33];
    __shared__ float Bs[16][64];
    __shared__ float invs[128];
    __shared__ float shs[128];
    int t = threadIdx.x;
    if (t < 128) {
        float iv = g[t] / sqrtf(vv[t] + BN_EPS);
        invs[t] = iv;
        shs[t] = cb[t] * iv + (bb[t] - mbn[t] * iv);
    }

    int m0 = blockIdx.x * 32;
    int n0 = blockIdx.y * 64;
    int tx = t & 15, ty = t >> 4;          // micro: rows ty*2+{0,1}, cols tx*4..
    int am = t >> 3, ak2 = (t & 7) * 2;    // A-stage: row am, k pair ak2
    int mm = m0 + am;
    int b = mm >> 10, rem = mm & 1023, y = rem >> 5, x = rem & 31;
    int xp = x >> 1, odd = x & 1, half = y >> 4, yy = y & 15;
    int toff = yy * 16 + xp;
    size_t cbase = ((size_t)((b * 64 + half) * 256 + toff)) * 8 + odd * 4 + (ak2 & 3)
                 + (size_t)(ak2 >> 2) * 4096;
    const float* p0 = c2p + cbase;
    const float* p1 = c2p + 1048576 + cbase;
    __syncthreads();   // invs/shs ready

    float acc[2][4] = {};
    for (int k0 = 0; k0 < 128; k0 += 16) {
        int k = k0 + ak2;
        float2 u = *(const float2*)&p0[(size_t)k0 * 1024];
        float2 w2 = *(const float2*)&p1[(size_t)k0 * 1024];
        float2 av;
        av.x = relu_f((u.x + w2.x) * invs[k] + shs[k]);
        av.y = relu_f((u.y + w2.y) * invs[k + 1] + shs[k + 1]);
        float4 bv = *(const float4*)&B[(size_t)(k0 + ty) * 256 + n0 + tx * 4];
        __syncthreads();
        As[ak2][am] = av.x;
        As[ak2 + 1][am] = av.y;
        *(float4*)&Bs[ty][tx * 4] = bv;
        __syncthreads();
#pragma unroll
        for (int kk = 0; kk < 16; ++kk) {
            float a0 = As[kk][ty * 2], a1 = As[kk][ty * 2 + 1];
            float4 b4 = *(const float4*)&Bs[kk][tx * 4];
            acc[0][0] += a0 * b4.x; acc[0][1] += a0 * b4.y;
            acc[0][2] += a0 * b4.z; acc[0][3] += a0 * b4.w;
            acc[1][0] += a1 * b4.x; acc[1][1] += a1 * b4.y;
            acc[1][2] += a1 * b4.z; acc[1][3] += a1 * b4.w;
        }
    }
#pragma unroll
    for (int i = 0; i < 2; ++i) {
        float4 o = {acc[i][0], acc[i][1], acc[i][2], acc[i][3]};
        *(float4*)&C[(size_t)(m0 + ty * 2 + i) * 256 + n0 + tx * 4] = o;
    }

    if (m0 < 1024) {
        float4 as4 = *(const float4*)&asrc[n0 + tx * 4];
        float4 ad4 = *(const float4*)&adst[n0 + tx * 4];
#pragma unroll
        for (int i = 0; i < 2; ++i) {
            float ss = acc[i][0] * as4.x + acc[i][1] * as4.y +
                       acc[i][2] * as4.z + acc[i][3] * as4.w;
            float dd = acc[i][0] * ad4.x + acc[i][1] * ad4.y +
                       acc[i][2] * ad4.z + acc[i][3] * ad4.w;
#pragma unroll
            for (int off = 1; off < 16; off <<= 1) {
                ss += __shfl_xor(ss, off);
                dd += __shfl_xor(dd, off);
            }
            if (tx == 0) {
                sp[blockIdx.y * 1024 + m0 + ty * 2 + i] = ss;
                dp[blockIdx.y * 1024 + m0 + ty * 2 + i] = dd;
            }
        }
    }
}

// ---------------- gemm2: h2 = x1 @ g2w, fused combine1 (rows<1024) + self (rows>=1024) ----
// rows<1024: A[m][k] = relu((sum_ks pacc1)*rden[m] + b1[k]) built on load.
// rows>=1024: A[m][k] = relu(h1[m][k] + b1[k]).
// grid (256, 2), 256 threads; score epilogue for m0<1024.
__global__ void gemm2_fused(const float* __restrict__ pacc1, const float* __restrict__ pden1,
                            const float* __restrict__ b1, const float* __restrict__ h1,
                            const float* __restrict__ B, float* __restrict__ C,
                            const float* __restrict__ asrc, const float* __restrict__ adst,
                            float* __restrict__ sp, float* __restrict__ dp)
{
    __shared__ float As[16][33];
    __shared__ float Bs[16][64];
    int t = threadIdx.x;
    int m0 = blockIdx.x * 32;
    int n0 = blockIdx.y * 64;
    int tx = t & 15, ty = t >> 4;
    int am = t >> 3, ak2 = (t & 7) * 2;
    int mm = m0 + am;
    bool lo = m0 < 1024;

    float rden = 0.f;
    const float* ap;
    if (lo) {
        float den = 0.f;
#pragma unroll
        for (int ks = 0; ks < 8; ++ks) den += pden1[ks * 1024 + mm];
        rden = 1.f / den;
        ap = pacc1 + (size_t)mm * 256 + ak2;
    } else {
        ap = h1 + (size_t)mm * 256 + ak2;
    }

    float acc[2][4] = {};
    for (int k0 = 0; k0 < 256; k0 += 16) {
        float2 av;
        float z0 = b1[k0 + ak2], z1 = b1[k0 + ak2 + 1];
        if (lo) {
            float sx = 0.f, sy = 0.f;
#pragma unroll
            for (int ks = 0; ks < 8; ++ks) {
                float2 u = *(const float2*)&ap[(size_t)ks * 262144 + k0];
                sx += u.x; sy += u.y;
            }
            av.x = relu_f(sx * rden + z0);
            av.y = relu_f(sy * rden + z1);
        } else {
            float2 u = *(const float2*)&ap[k0];
            av.x = relu_f(u.x + z0);
            av.y = relu_f(u.y + z1);
        }
        float4 bv = *(const float4*)&B[(size_t)(k0 + ty) * 128 + n0 + tx * 4];
        __syncthreads();
        As[ak2][am] = av.x;
        As[ak2 + 1][am] = av.y;
        *(float4*)&Bs[ty][tx * 4] = bv;
        __syncthreads();
#pragma unroll
        for (int kk = 0; kk < 16; ++kk) {
            float a0 = As[kk][ty * 2], a1 = As[kk][ty * 2 + 1];
            float4 b4 = *(const float4*)&Bs[kk][tx * 4];
            acc[0][0] += a0 * b4.x; acc[0][1] += a0 * b4.y;
            acc[0][2] += a0 * b4.z; acc[0][3] += a0 * b4.w;
            acc[1][0] += a1 * b4.x; acc[1][1] += a1 * b4.y;
            acc[1][2] += a1 * b4.z; acc[1][3] += a1 * b4.w;
        }
    }
#pragma unroll
    for (int i = 0; i < 2; ++i) {
        float4 o = {acc[i][0], acc[i][1], acc[i][2], acc[i][3]};
        *(float4*)&C[(size_t)(m0 + ty * 2 + i) * 128 + n0 + tx * 4] = o;
    }

    if (lo) {
        float4 as4 = *(const float4*)&asrc[n0 + tx * 4];
        float4 ad4 = *(const float4*)&adst[n0 + tx * 4];
#pragma unroll
        for (int i = 0; i < 2; ++i) {
            float ss = acc[i][0] * as4.x + acc[i][1] * as4.y +
                       acc[i][2] * as4.z + acc[i][3] * as4.w;
            float dd = acc[i][0] * ad4.x + acc[i][1] * ad4.y +
                       acc[i][2] * ad4.z + acc[i][3] * ad4.w;
#pragma unroll
            for (int off = 1; off < 16; off <<= 1) {
                ss += __shfl_xor(ss, off);
                dd += __shfl_xor(dd, off);
            }
            if (tx == 0) {
                sp[blockIdx.y * 1024 + m0 + ty * 2 + i] = ss;
                dp[blockIdx.y * 1024 + m0 + ty * 2 + i] = dd;
            }
        }
    }
}

// ---------------- GAT aggregation split-K GEMM, 32x64 tile, 256 threads (4 waves) ----------
// C[v,c] = sum_u exp(leaky(s[u]+d[v]) - m[v]) * h[u,c];  m[v] = leaky(smax + d[v])
// s/d come as NT per-n-tile partials (sp[nt*1024+u]); summed at staging (deterministic).
// grid (32, D/64, KS)
template <int D, int KS, int NT>
__global__ void gat_agg_gemm(const float* __restrict__ h, const float* __restrict__ sp,
                             const float* __restrict__ dp, float* __restrict__ pacc,
                             float* __restrict__ pden)
{
    __shared__ float Ss[1024];
    __shared__ float As[16][33];
    __shared__ float Bs[16][64];
    __shared__ float red[4];
    __shared__ float part[16][32];

    const int CH = 1024 / KS;
    int t = threadIdx.x;
    int m0 = blockIdx.x * 32;
    int n0 = blockIdx.y * 64;
    int kz = blockIdx.z;
    int tx = t & 15, ty = t >> 4;
    int vg2 = tx * 2;                      // A-gen: u-row=ty, v-cols vg2,vg2+1

    // stage s (4 per thread, summing NT partials) + global max
    float4 sa = {0.f, 0.f, 0.f, 0.f};
#pragma unroll
    for (int nt = 0; nt < NT; ++nt) {
        float4 u = *(const float4*)&sp[nt * 1024 + t * 4];
        sa.x += u.x; sa.y += u.y; sa.z += u.z; sa.w += u.w;
    }
    *(float4*)&Ss[t * 4] = sa;
    float lm = fmaxf(fmaxf(sa.x, sa.y), fmaxf(sa.z, sa.w));
#pragma unroll
    for (int off = 1; off < 64; off <<= 1) lm = fmaxf(lm, __shfl_xor(lm, off));
    if ((t & 63) == 0) red[t >> 6] = lm;
    __syncthreads();
    float smax = fmaxf(fmaxf(red[0], red[1]), fmaxf(red[2], red[3]));

    float dv0 = 0.f, dv1 = 0.f;
#pragma unroll
    for (int nt = 0; nt < NT; ++nt) {
        dv0 += dp[nt * 1024 + m0 + vg2];
        dv1 += dp[nt * 1024 + m0 + vg2 + 1];
    }
    float mv0 = leaky_f(smax + dv0), mv1 = leaky_f(smax + dv1);
    float ds0 = 0.f, ds1 = 0.f;
    float acc[2][4] = {};

    for (int k0 = kz * CH; k0 < kz * CH + CH; k0 += 16) {
        float4 bv = *(const float4*)&h[(size_t)(k0 + ty) * D + n0 + tx * 4];
        float su = Ss[k0 + ty];
        float a0 = __expf(leaky_f(su + dv0) - mv0);
        float a1 = __expf(leaky_f(su + dv1) - mv1);
        ds0 += a0; ds1 += a1;
        __syncthreads();
        As[ty][vg2] = a0;
        As[ty][vg2 + 1] = a1;
        *(float4*)&Bs[ty][tx * 4] = bv;
        __syncthreads();
#pragma unroll
        for (int kk = 0; kk < 16; ++kk) {
            float a0m = As[kk][ty * 2], a1m = As[kk][ty * 2 + 1];
            float4 b4 = *(const float4*)&Bs[kk][tx * 4];
            acc[0][0] += a0m * b4.x; acc[0][1] += a0m * b4.y;
            acc[0][2] += a0m * b4.z; acc[0][3] += a0m * b4.w;
            acc[1][0] += a1m * b4.x; acc[1][1] += a1m * b4.y;
            acc[1][2] += a1m * b4.z; acc[1][3] += a1m * b4.w;
        }
    }

    __syncthreads();
    part[ty][vg2] = ds0;
    part[ty][vg2 + 1] = ds1;
    __syncthreads();

#pragma unroll
    for (int i = 0; i < 2; ++i) {
        float4 o = {acc[i][0], acc[i][1], acc[i][2], acc[i][3]};
        *(float4*)&pacc[((size_t)kz * 1024 + m0 + ty * 2 + i) * D + n0 + tx * 4] = o;
    }
    if (t < 32) {
        float den = 0.f;
#pragma unroll
        for (int u = 0; u < 16; ++u) den += part[u][t];
        pden[kz * 1024 + m0 + t] = den;   // redundant across n0-blocks: same value, benign
    }
}

// ---------------- mean-pool (fused combine2 for image 0 + self-transform for b>=1) --------
// 128 blocks = b(8) x seg(16), 128 threads (thread = channel).
// b==0: rows<1024 combined from 16 pacc2 planes on the fly (x2 never materialized).
// b>=1: relu(h2 + b2) on the fly.
__global__ void pool_combine(const float* __restrict__ pacc2, const float* __restrict__ pden2,
                             const float* __restrict__ h2, const float* __restrict__ b2,
                             float* __restrict__ part)
{
    __shared__ float dinv[64];
    int blk = blockIdx.x;
    int b = blk >> 4, seg = blk & 15, t = threadIdx.x;
    float bz = b2[t];
    float acc = 0.f;
    if (b == 0) {
        if (t < 64) {
            int v = seg * 64 + t;
            float den = 0.f;
#pragma unroll
            for (int ks = 0; ks < 16; ++ks) den += pden2[ks * 1024 + v];
            dinv[t] = 1.f / den;
        }
        __syncthreads();
        for (int n = 0; n < 64; ++n) {
            int v = seg * 64 + n;
            float s = 0.f;
#pragma unroll
            for (int ks = 0; ks < 16; ++ks)
                s += pacc2[(size_t)(ks * 1024 + v) * 128 + t];
            acc += relu_f(s * dinv[n] + bz);
        }
    } else {
        const float* p = h2 + ((size_t)b * 1024 + seg * 64) * 128 + t;
#pragma unroll 8
        for (int n = 0; n < 64; ++n) acc += relu_f(p[(size_t)n * 128] + bz);
    }
    part[(b * 16 + seg) * 128 + t] = acc;
}

// ---------------- head: reduce partials + linear + log_softmax ----------------
__global__ void head_kernel(const float* __restrict__ part, const float* __restrict__ ow,
                            const float* __restrict__ ob, float* __restrict__ out)
{
    __shared__ float pooled[128];
    __shared__ float logits[10];
    int b = blockIdx.x, t = threadIdx.x;
    float acc = 0.f;
#pragma unroll
    for (int sgi = 0; sgi < 16; ++sgi) acc += part[(b * 16 + sgi) * 128 + t];
    pooled[t] = acc * (1.f / 1024.f);
    __syncthreads();
    if (t < 10) {
        float l = ob[t];
        for (int c = 0; c < 128; ++c) l += pooled[c] * ow[c * 10 + t];
        logits[t] = l;
    }
    __syncthreads();
    if (t == 0) {
        float mx = logits[0];
        for (int j = 1; j < 10; ++j) mx = fmaxf(mx, logits[j]);
        float sum = 0.f;
        for (int j = 0; j < 10; ++j) sum += expf(logits[j] - mx);
        float lse = mx + logf(sum);
        for (int j = 0; j < 10; ++j) out[b * 10 + j] = logits[j] - lse;
    }
}

extern "C" void kernel_launch(void* const* d_in, const int* in_sizes, int n_in,
                              void* d_out, int out_size, void* d_ws, size_t ws_size,
                              hipStream_t stream)
{
    const float* images = (const float*)d_in[0];
    const float* c1w = (const float*)d_in[1];
    const float* c1b = (const float*)d_in[2];
    const float* bn1g = (const float*)d_in[3];
    const float* bn1b = (const float*)d_in[4];
    const float* bn1m = (const float*)d_in[5];
    const float* bn1v = (const float*)d_in[6];
    const float* c2w = (const float*)d_in[7];
    const float* c2b = (const float*)d_in[8];
    const float* bn2g = (const float*)d_in[9];
    const float* bn2b = (const float*)d_in[10];
    const float* bn2m = (const float*)d_in[11];
    const float* bn2v = (const float*)d_in[12];
    const float* g1w = (const float*)d_in[13];
    const float* g1as = (const float*)d_in[14];
    const float* g1ad = (const float*)d_in[15];
    const float* g1b = (const float*)d_in[16];
    const float* g2w = (const float*)d_in[17];
    const float* g2as = (const float*)d_in[18];
    const float* g2ad = (const float*)d_in[19];
    const float* g2b = (const float*)d_in[20];
    const float* ow = (const float*)d_in[21];
    const float* ob = (const float*)d_in[22];
    float* out = (float*)d_out;

    // ws layout (floats), ~21 MB:
    //   A = ws+0        (2M): c2p planes (K2-K3), then pacc1 (K4-K5)     [c2p dead before K4]
    //   B = ws+2M       (2M): h1 (K3-K5), then pacc2 (K6-K7)             [h1 dead after K5]
    //   C = ws+4M       (1M): bufc1 (K1-K2), then h2 (K5-K7)             [bufc1 dead after K2]
    //   smalls at ws+5M: sp1,dp1,sp2,dp2,pden1,pden2,part
    float* ws = (float*)d_ws;
    float* c2p   = ws;                    // 2,097,152
    float* pacc1 = ws;                    // 8*1024*256
    float* h1    = ws + 2097152;          // 2,097,152
    float* pacc2 = ws + 2097152;          // 16*1024*128
    float* bufc1 = ws + 4194304;          //   524,288
    float* h2    = ws + 4194304;          // 1,048,576
    float* sp1   = ws + 5242880;          // 4,096
    float* dp1   = ws + 5246976;          // 4,096
    float* sp2   = ws + 5251072;          // 2,048
    float* dp2   = ws + 5253120;          // 2,048
    float* pden1 = ws + 5255168;          // 8,192
    float* pden2 = ws + 5263360;          // 16,384
    float* part  = ws + 5279744;          // 16,384

    conv1_pool<<<512, 256, 0, stream>>>(images, c1w, c1b, bn1g, bn1b, bn1m, bn1v, bufc1);
    conv2_split<<<1024, 256, 0, stream>>>(bufc1, c2w, c2p);

    gemm1_conv<<<dim3(256, 4), 256, 0, stream>>>(
        c2p, c2b, bn2g, bn2b, bn2m, bn2v, g1w, h1, g1as, g1ad, sp1, dp1);
    gat_agg_gemm<256, 8, 4><<<dim3(32, 4, 8), 256, 0, stream>>>(h1, sp1, dp1, pacc1, pden1);

    gemm2_fused<<<dim3(256, 2), 256, 0, stream>>>(
        pacc1, pden1, g1b, h1, g2w, h2, g2as, g2ad, sp2, dp2);
    gat_agg_gemm<128, 16, 2><<<dim3(32, 2, 16), 256, 0, stream>>>(h2, sp2, dp2, pacc2, pden2);

    pool_combine<<<128, 128, 0, stream>>>(pacc2, pden2, h2, g2b, part);
    head_kernel<<<8, 128, 0, stream>>>(part, ow, ob, out);
}

// Round 7
// 203.815 us; speedup vs baseline: 1.1533x; 1.1533x over previous
//
#include <hip/hip_runtime.h>
#include <math.h>

#define BN_EPS 1e-5f
#define NEG_SLOPE 0.2f

__device__ __forceinline__ float relu_f(float x) { return x > 0.f ? x : 0.f; }
__device__ __forceinline__ float leaky_f(float z) { return z > 0.f ? z : NEG_SLOPE * z; }

// ---------------- conv1 (3->64, 3x3 SAME) fused bias+BN+ReLU+2x2maxpool ----------------
// grid 512 = b(8) x cog(16) x q(4); 256 threads = one pooled position, 4 co
__global__ void conv1_pool(const float* __restrict__ img, const float* __restrict__ w,
                           const float* __restrict__ cb, const float* __restrict__ g,
                           const float* __restrict__ bb, const float* __restrict__ m,
                           const float* __restrict__ vv, float* __restrict__ out)
{
    int blk = blockIdx.x;
    int q = blk & 3, cog = (blk >> 2) & 15, b = blk >> 6;
    int t = threadIdx.x;
    int x = t & 31, y = (q << 3) + (t >> 5);

    float acc[4][4] = {};
#pragma unroll
    for (int ci = 0; ci < 3; ++ci) {
        const float* ib = img + (b * 3 + ci) * 4096;
        float rv[4][4];
#pragma unroll
        for (int r = 0; r < 4; ++r) {
            int yy = 2 * y - 1 + r;
            bool yok = (unsigned)yy < 64u;
            const float* p = ib + yy * 64 + 2 * x;
            float2 c01 = yok ? *(const float2*)p : make_float2(0.f, 0.f);
            rv[r][1] = c01.x;
            rv[r][2] = c01.y;
            rv[r][0] = (yok && x > 0) ? p[-1] : 0.f;
            rv[r][3] = (yok && x < 31) ? p[2] : 0.f;
        }
#pragma unroll
        for (int j = 0; j < 4; ++j) {
            const float* wj = w + ((cog * 4 + j) * 3 + ci) * 9;
#pragma unroll
            for (int ky = 0; ky < 3; ++ky)
#pragma unroll
                for (int kx = 0; kx < 3; ++kx) {
                    float wvv = wj[ky * 3 + kx];
#pragma unroll
                    for (int py = 0; py < 2; ++py)
#pragma unroll
                        for (int px = 0; px < 2; ++px)
                            acc[j][py * 2 + px] += rv[py + ky][px + kx] * wvv;
                }
        }
    }
#pragma unroll
    for (int j = 0; j < 4; ++j) {
        int co = cog * 4 + j;
        float inv = g[co] / sqrtf(vv[co] + BN_EPS);
        float sh = cb[co] * inv + (bb[co] - m[co] * inv);
        float v0 = relu_f(acc[j][0] * inv + sh);
        float v1 = relu_f(acc[j][1] * inv + sh);
        float v2 = relu_f(acc[j][2] * inv + sh);
        float v3 = relu_f(acc[j][3] * inv + sh);
        out[((b * 64 + co) * 32 + y) * 32 + x] = fmaxf(fmaxf(v0, v1), fmaxf(v2, v3));
    }
}

// ---------------- conv2: 64->128, 3x3 SAME, SPLIT-K over ci (2 ways) ----------------
// grid 1024 = b(8) x cog(32) x half(2) x kz(2); 256 threads; each block reduces 32 ci.
// Partials BLOCK-LINEAR (fully coalesced): plane[kz] at ((bid*256+t)*8), bid=b*64+cog*2+half
__global__ void conv2_split(const float* __restrict__ in, const float* __restrict__ w,
                            float* __restrict__ c2p)
{
    int blk = blockIdx.x;
    int kz = blk & 1, half = (blk >> 1) & 1, cog = (blk >> 2) & 31, b = blk >> 7;
    int t = threadIdx.x;
    int x2p = (t & 15) * 2;
    int y = half * 16 + (t >> 4);
    bool xnz = x2p != 0;
    bool xhi = x2p == 30;
    const float* ibase = in + b * 65536 + kz * 32768;
    int xb = xnz ? x2p - 1 : 0;

    float acc[4][2] = {};

#pragma unroll 2
    for (int ci = 0; ci < 32; ++ci) {
        const float* cb2 = ibase + ci * 1024;
        float rc[3][4];
#pragma unroll
        for (int r = 0; r < 3; ++r) {
            int yy = y - 1 + r;
            bool yok = (unsigned)yy < 32u;
            const float* p = cb2 + yy * 32 + xb;
            float4 f = yok ? *(const float4*)p : make_float4(0.f, 0.f, 0.f, 0.f);
            rc[r][0] = xnz ? f.x : 0.f;
            rc[r][1] = xnz ? f.y : f.x;
            rc[r][2] = xnz ? f.z : f.y;
            float r3 = xnz ? f.w : f.z;
            rc[r][3] = xhi ? 0.f : r3;
        }
#pragma unroll
        for (int j = 0; j < 4; ++j) {
            const float* wj = w + ((cog * 4 + j) * 64 + kz * 32 + ci) * 9;
#pragma unroll
            for (int ky = 0; ky < 3; ++ky)
#pragma unroll
                for (int kx = 0; kx < 3; ++kx) {
                    float wvv = wj[ky * 3 + kx];
                    acc[j][0] += rc[ky][kx] * wvv;
                    acc[j][1] += rc[ky][kx + 1] * wvv;
                }
        }
    }

    float* pp = c2p + (size_t)kz * 1048576;
    int bid = b * 64 + cog * 2 + half;
    size_t base = ((size_t)bid * 256 + t) * 8;
    float4 s0 = {acc[0][0], acc[1][0], acc[2][0], acc[3][0]};
    float4 s1 = {acc[0][1], acc[1][1], acc[2][1], acc[3][1]};
    *(float4*)&pp[base] = s0;
    *(float4*)&pp[base + 4] = s1;
}

// combine 2 kz planes (block-linear layout) + bias + BN + ReLU -> x0 [n][128]
// grid 512 x 256; reads fully coalesced, scattered 16B writes only on the 4MB output
__global__ void conv2_combine(const float* __restrict__ c2p,
                              const float* __restrict__ cb, const float* __restrict__ g,
                              const float* __restrict__ bb, const float* __restrict__ m,
                              const float* __restrict__ vv, float* __restrict__ x0)
{
    int gid = blockIdx.x * 256 + threadIdx.x;   // [0, 131072)
    int t = gid & 255, bid = gid >> 8;
    int half = bid & 1, cog = (bid >> 1) & 31, b = bid >> 6;
    size_t off = (size_t)gid * 8;

    float4 u0 = *(const float4*)&c2p[off];
    float4 u1 = *(const float4*)&c2p[off + 4];
    float4 w0 = *(const float4*)&c2p[1048576 + off];
    float4 w1 = *(const float4*)&c2p[1048576 + off + 4];
    float sx = u0.x + w0.x, sy = u0.y + w0.y, sz = u0.z + w0.z, sw = u0.w + w0.w;
    float qx = u1.x + w1.x, qy = u1.y + w1.y, qz = u1.z + w1.z, qw = u1.w + w1.w;

    float4 gg = ((const float4*)g)[cog];
    float4 vvv = ((const float4*)vv)[cog];
    float4 bbb = ((const float4*)bb)[cog];
    float4 mm = ((const float4*)m)[cog];
    float4 cbb = ((const float4*)cb)[cog];
    float ix = gg.x / sqrtf(vvv.x + BN_EPS);
    float iy = gg.y / sqrtf(vvv.y + BN_EPS);
    float iz = gg.z / sqrtf(vvv.z + BN_EPS);
    float iw = gg.w / sqrtf(vvv.w + BN_EPS);
    float shx = cbb.x * ix + (bbb.x - mm.x * ix);
    float shy = cbb.y * iy + (bbb.y - mm.y * iy);
    float shz = cbb.z * iz + (bbb.z - mm.z * iz);
    float shw = cbb.w * iw + (bbb.w - mm.w * iw);

    float4 o0 = {relu_f(sx * ix + shx), relu_f(sy * iy + shy),
                 relu_f(sz * iz + shz), relu_f(sw * iw + shw)};
    float4 o1 = {relu_f(qx * ix + shx), relu_f(qy * iy + shy),
                 relu_f(qz * iz + shz), relu_f(qw * iw + shw)};

    int y = half * 16 + (t >> 4), x2p = (t & 15) * 2;
    int n0 = b * 1024 + y * 32 + x2p;
    *(float4*)&x0[(size_t)n0 * 128 + cog * 4] = o0;
    *(float4*)&x0[(size_t)(n0 + 1) * 128 + cog * 4] = o1;
}

// ---------------- tiled GEMM: 32x64 tile, 256 threads (4 waves), 2x4 micro ----------------
// grid (M/32, N/64).
// SELF: rows >= 1024 read Ahi and apply relu(a + abias) on load (fused self-loop path).
// SCORE: blocks with m0<1024 also emit per-n-tile partial attention scores:
//   sp[by*1024 + row] = sum_{c in this 64-col slice} C[row,c]*asrc[c]   (dp likewise)
template <int K, int N, bool SELF, bool SCORE>
__global__ void gemm32(const float* __restrict__ A, const float* __restrict__ Ahi,
                       const float* __restrict__ abias,
                       const float* __restrict__ B, float* __restrict__ C,
                       const float* __restrict__ asrc, const float* __restrict__ adst,
                       float* __restrict__ sp, float* __restrict__ dp)
{
    __shared__ float As[16][33];
    __shared__ float Bs[16][64];
    int t = threadIdx.x;
    int m0 = blockIdx.x * 32;
    int n0 = blockIdx.y * 64;
    int tx = t & 15, ty = t >> 4;          // micro: rows ty*2+{0,1}, cols tx*4..
    int am = t >> 3, ak2 = (t & 7) * 2;    // A-stage: row am, k pair ak2
    bool hi = SELF && m0 >= 1024;
    const float* Ab = hi ? Ahi : A;
    float acc[2][4] = {};

    for (int k0 = 0; k0 < K; k0 += 16) {
        float2 av = *(const float2*)&Ab[(size_t)(m0 + am) * K + k0 + ak2];
        if (hi) {
            av.x = relu_f(av.x + abias[k0 + ak2]);
            av.y = relu_f(av.y + abias[k0 + ak2 + 1]);
        }
        float4 bv = *(const float4*)&B[(size_t)(k0 + ty) * N + n0 + tx * 4];
        __syncthreads();
        As[ak2][am] = av.x;
        As[ak2 + 1][am] = av.y;
        *(float4*)&Bs[ty][tx * 4] = bv;
        __syncthreads();
#pragma unroll
        for (int kk = 0; kk < 16; ++kk) {
            float a0 = As[kk][ty * 2], a1 = As[kk][ty * 2 + 1];
            float4 b4 = *(const float4*)&Bs[kk][tx * 4];
            acc[0][0] += a0 * b4.x; acc[0][1] += a0 * b4.y;
            acc[0][2] += a0 * b4.z; acc[0][3] += a0 * b4.w;
            acc[1][0] += a1 * b4.x; acc[1][1] += a1 * b4.y;
            acc[1][2] += a1 * b4.z; acc[1][3] += a1 * b4.w;
        }
    }
#pragma unroll
    for (int i = 0; i < 2; ++i) {
        float4 o = {acc[i][0], acc[i][1], acc[i][2], acc[i][3]};
        *(float4*)&C[(size_t)(m0 + ty * 2 + i) * N + n0 + tx * 4] = o;
    }

    if (SCORE && m0 < 1024) {
        float4 as4 = *(const float4*)&asrc[n0 + tx * 4];
        float4 ad4 = *(const float4*)&adst[n0 + tx * 4];
#pragma unroll
        for (int i = 0; i < 2; ++i) {
            float ss = acc[i][0] * as4.x + acc[i][1] * as4.y +
                       acc[i][2] * as4.z + acc[i][3] * as4.w;
            float dd = acc[i][0] * ad4.x + acc[i][1] * ad4.y +
                       acc[i][2] * ad4.z + acc[i][3] * ad4.w;
#pragma unroll
            for (int off = 1; off < 16; off <<= 1) {
                ss += __shfl_xor(ss, off);
                dd += __shfl_xor(dd, off);
            }
            if (tx == 0) {
                sp[blockIdx.y * 1024 + m0 + ty * 2 + i] = ss;
                dp[blockIdx.y * 1024 + m0 + ty * 2 + i] = dd;
            }
        }
    }
}

// ---------------- GAT aggregation split-K GEMM, 32x64 tile, 256 threads (4 waves) ----------
// C[v,c] = sum_u exp(leaky(s[u]+d[v]) - m[v]) * h[u,c];  m[v] = leaky(smax + d[v])
// s/d come as NT per-n-tile partials (sp[nt*1024+u]); summed at staging (deterministic).
// grid (32, D/64, KS)
template <int D, int KS, int NT>
__global__ void gat_agg_gemm(const float* __restrict__ h, const float* __restrict__ sp,
                             const float* __restrict__ dp, float* __restrict__ pacc,
                             float* __restrict__ pden)
{
    __shared__ float Ss[1024];
    __shared__ float As[16][33];
    __shared__ float Bs[16][64];
    __shared__ float red[4];
    __shared__ float part[16][32];

    const int CH = 1024 / KS;
    int t = threadIdx.x;
    int m0 = blockIdx.x * 32;
    int n0 = blockIdx.y * 64;
    int kz = blockIdx.z;
    int tx = t & 15, ty = t >> 4;
    int vg2 = tx * 2;                      // A-gen: u-row=ty, v-cols vg2,vg2+1

    // stage s (4 per thread, summing NT partials) + global max
    float4 sa = {0.f, 0.f, 0.f, 0.f};
#pragma unroll
    for (int nt = 0; nt < NT; ++nt) {
        float4 u = *(const float4*)&sp[nt * 1024 + t * 4];
        sa.x += u.x; sa.y += u.y; sa.z += u.z; sa.w += u.w;
    }
    *(float4*)&Ss[t * 4] = sa;
    float lm = fmaxf(fmaxf(sa.x, sa.y), fmaxf(sa.z, sa.w));
#pragma unroll
    for (int off = 1; off < 64; off <<= 1) lm = fmaxf(lm, __shfl_xor(lm, off));
    if ((t & 63) == 0) red[t >> 6] = lm;
    __syncthreads();
    float smax = fmaxf(fmaxf(red[0], red[1]), fmaxf(red[2], red[3]));

    float dv0 = 0.f, dv1 = 0.f;
#pragma unroll
    for (int nt = 0; nt < NT; ++nt) {
        dv0 += dp[nt * 1024 + m0 + vg2];
        dv1 += dp[nt * 1024 + m0 + vg2 + 1];
    }
    float mv0 = leaky_f(smax + dv0), mv1 = leaky_f(smax + dv1);
    float ds0 = 0.f, ds1 = 0.f;
    float acc[2][4] = {};

    for (int k0 = kz * CH; k0 < kz * CH + CH; k0 += 16) {
        float4 bv = *(const float4*)&h[(size_t)(k0 + ty) * D + n0 + tx * 4];
        float su = Ss[k0 + ty];
        float a0 = __expf(leaky_f(su + dv0) - mv0);
        float a1 = __expf(leaky_f(su + dv1) - mv1);
        ds0 += a0; ds1 += a1;
        __syncthreads();
        As[ty][vg2] = a0;
        As[ty][vg2 + 1] = a1;
        *(float4*)&Bs[ty][tx * 4] = bv;
        __syncthreads();
#pragma unroll
        for (int kk = 0; kk < 16; ++kk) {
            float a0m = As[kk][ty * 2], a1m = As[kk][ty * 2 + 1];
            float4 b4 = *(const float4*)&Bs[kk][tx * 4];
            acc[0][0] += a0m * b4.x; acc[0][1] += a0m * b4.y;
            acc[0][2] += a0m * b4.z; acc[0][3] += a0m * b4.w;
            acc[1][0] += a1m * b4.x; acc[1][1] += a1m * b4.y;
            acc[1][2] += a1m * b4.z; acc[1][3] += a1m * b4.w;
        }
    }

    __syncthreads();
    part[ty][vg2] = ds0;
    part[ty][vg2 + 1] = ds1;
    __syncthreads();

#pragma unroll
    for (int i = 0; i < 2; ++i) {
        float4 o = {acc[i][0], acc[i][1], acc[i][2], acc[i][3]};
        *(float4*)&pacc[((size_t)kz * 1024 + m0 + ty * 2 + i) * D + n0 + tx * 4] = o;
    }
    if (t < 32) {
        float den = 0.f;
#pragma unroll
        for (int u = 0; u < 16; ++u) den += part[u][t];
        pden[kz * 1024 + m0 + t] = den;   // redundant across n0-blocks: same value, benign
    }
}

// combine split-K partials: out[v,c] = relu(sum_ks pacc / sum_ks pden + bias), v < 1024
template <int D, int KS>
__global__ void gat_combine(const float* __restrict__ pacc, const float* __restrict__ pden,
                            const float* __restrict__ bias, float* __restrict__ out)
{
    int idx = blockIdx.x * blockDim.x + threadIdx.x;
    if (idx >= 1024 * D / 4) return;
    int c4 = idx & (D / 4 - 1);
    int v = idx / (D / 4);
    float4 a = {0.f, 0.f, 0.f, 0.f};
    float den = 0.f;
#pragma unroll
    for (int ks = 0; ks < KS; ++ks) {
        float4 p = ((const float4*)pacc)[(size_t)(ks * 1024 + v) * (D / 4) + c4];
        a.x += p.x; a.y += p.y; a.z += p.z; a.w += p.w;
        den += pden[ks * 1024 + v];
    }
    float rd = 1.f / den;
    float4 bz = ((const float4*)bias)[c4];
    float4 o = {relu_f(a.x * rd + bz.x), relu_f(a.y * rd + bz.y),
                relu_f(a.z * rd + bz.z), relu_f(a.w * rd + bz.w)};
    ((float4*)out)[(size_t)v * (D / 4) + c4] = o;
}

// ---------------- mean-pool stage 1 (fused self-transform): 128 blocks, each sums 64 rows ----
// image 0 reads x2 (already relu'd); images 1..7 read relu(h2 + g2b) on the fly
__global__ void pool_part(const float* __restrict__ x2, const float* __restrict__ h2,
                          const float* __restrict__ bias2, float* __restrict__ part)
{
    int b = blockIdx.x >> 4, seg = blockIdx.x & 15, t = threadIdx.x;
    float acc = 0.f;
    if (b == 0) {
        const float* p = x2 + ((size_t)seg * 64) * 128 + t;
#pragma unroll 8
        for (int n = 0; n < 64; ++n) acc += p[(size_t)n * 128];
    } else {
        float bz = bias2[t];
        const float* p = h2 + ((size_t)b * 1024 + seg * 64) * 128 + t;
#pragma unroll 8
        for (int n = 0; n < 64; ++n) acc += relu_f(p[(size_t)n * 128] + bz);
    }
    part[(b * 16 + seg) * 128 + t] = acc;
}

// ---------------- head: reduce partials + linear + log_softmax ----------------
__global__ void head_kernel(const float* __restrict__ part, const float* __restrict__ ow,
                            const float* __restrict__ ob, float* __restrict__ out)
{
    __shared__ float pooled[128];
    __shared__ float logits[10];
    int b = blockIdx.x, t = threadIdx.x;
    float acc = 0.f;
#pragma unroll
    for (int sgi = 0; sgi < 16; ++sgi) acc += part[(b * 16 + sgi) * 128 + t];
    pooled[t] = acc * (1.f / 1024.f);
    __syncthreads();
    if (t < 10) {
        float l = ob[t];
        for (int c = 0; c < 128; ++c) l += pooled[c] * ow[c * 10 + t];
        logits[t] = l;
    }
    __syncthreads();
    if (t == 0) {
        float mx = logits[0];
        for (int j = 1; j < 10; ++j) mx = fmaxf(mx, logits[j]);
        float sum = 0.f;
        for (int j = 0; j < 10; ++j) sum += expf(logits[j] - mx);
        float lse = mx + logf(sum);
        for (int j = 0; j < 10; ++j) out[b * 10 + j] = logits[j] - lse;
    }
}

extern "C" void kernel_launch(void* const* d_in, const int* in_sizes, int n_in,
                              void* d_out, int out_size, void* d_ws, size_t ws_size,
                              hipStream_t stream)
{
    const float* images = (const float*)d_in[0];
    const float* c1w = (const float*)d_in[1];
    const float* c1b = (const float*)d_in[2];
    const float* bn1g = (const float*)d_in[3];
    const float* bn1b = (const float*)d_in[4];
    const float* bn1m = (const float*)d_in[5];
    const float* bn1v = (const float*)d_in[6];
    const float* c2w = (const float*)d_in[7];
    const float* c2b = (const float*)d_in[8];
    const float* bn2g = (const float*)d_in[9];
    const float* bn2b = (const float*)d_in[10];
    const float* bn2m = (const float*)d_in[11];
    const float* bn2v = (const float*)d_in[12];
    const float* g1w = (const float*)d_in[13];
    const float* g1as = (const float*)d_in[14];
    const float* g1ad = (const float*)d_in[15];
    const float* g1b = (const float*)d_in[16];
    const float* g2w = (const float*)d_in[17];
    const float* g2as = (const float*)d_in[18];
    const float* g2ad = (const float*)d_in[19];
    const float* g2b = (const float*)d_in[20];
    const float* ow = (const float*)d_in[21];
    const float* ob = (const float*)d_in[22];
    float* out = (float*)d_out;

    // ws layout (floats):
    // [x1 2,097,152][bufc1 524,288][h1 2,097,152][x0 1,048,576][h2 1,048,576][scores 28K]
    // conv2 planes (2x1M) alias x1 (dead till combine1). pacc1 (KS=4: 1M) aliases x0
    // (dead after gemm1). pacc2 (KS=8: 1M) aliases h1 (dead after gemm2, its last reader).
    // x2 = x0 (dead after combine1... x0 region reused by pacc1 then freed by combine1).
    float* ws = (float*)d_ws;
    float* x1    = ws;                   // 2,097,152
    float* bufc1 = ws + 2097152;         //   524,288
    float* h1    = ws + 2621440;         // 2,097,152
    float* x0    = ws + 4718592;         // 1,048,576
    float* h2    = ws + 5767168;         // 1,048,576
    float* sp1   = ws + 6815744;         // 4 x 1024 partial src-scores (per n-tile)
    float* dp1   = ws + 6819840;         // 4 x 1024
    float* sp2   = ws + 6823936;         // 2 x 1024
    float* dp2   = ws + 6825984;         // 2 x 1024
    float* part  = bufc1;                // 16,384 (bufc1 dead after conv2_split)
    float* pden1 = bufc1 + 16384;        // 4,096
    float* pden2 = bufc1 + 24576;        // 8,192
    float* pacc1 = x0;                   // 4*1024*256 = 1,048,576 (fits x0 exactly)
    float* pacc2 = h1;                   // 8*1024*128 = 1,048,576
    float* x2    = x0;
    float* c2p   = x1;                   // conv2 split planes 0,1 (2*1,048,576)

    conv1_pool<<<512, 256, 0, stream>>>(images, c1w, c1b, bn1g, bn1b, bn1m, bn1v, bufc1);
    conv2_split<<<1024, 256, 0, stream>>>(bufc1, c2w, c2p);
    conv2_combine<<<512, 256, 0, stream>>>(c2p, c2b, bn2g, bn2b, bn2m, bn2v, x0);

    // NOTE: gemm1 reads x0 and writes h1; pacc1 aliases x0 but is only written by agg1
    // AFTER gemm1 completes (stream-ordered), and x0 is dead past gemm1. Safe.
    gemm32<128, 256, false, true><<<dim3(256, 4), 256, 0, stream>>>(
        x0, x0, nullptr, g1w, h1, g1as, g1ad, sp1, dp1);
    gat_agg_gemm<256, 4, 4><<<dim3(32, 4, 4), 256, 0, stream>>>(h1, sp1, dp1, pacc1, pden1);
    gat_combine<256, 4><<<256, 256, 0, stream>>>(pacc1, pden1, g1b, x1);

    // gemm2: rows<1024 from x1; rows>=1024 = relu(h1+g1b) fused; + fused score2 partials
    gemm32<256, 128, true, true><<<dim3(256, 2), 256, 0, stream>>>(
        x1, h1, g1b, g2w, h2, g2as, g2ad, sp2, dp2);
    gat_agg_gemm<128, 8, 2><<<dim3(32, 2, 8), 256, 0, stream>>>(h2, sp2, dp2, pacc2, pden2);
    gat_combine<128, 8><<<128, 256, 0, stream>>>(pacc2, pden2, g2b, x2);

    pool_part<<<128, 128, 0, stream>>>(x2, h2, g2b, part);
    head_kernel<<<8, 128, 0, stream>>>(part, ow, ob, out);
}